// Round 3
// baseline (2416.472 us; speedup 1.0000x reference)
//
#include <hip/hip_runtime.h>
#include <math.h>

#define Dm    2048
#define Hh    6
#define DKk   256
#define DVv   512
#define KD    1536
#define VD    3072

typedef __attribute__((ext_vector_type(8))) __bf16 bf16x8;
typedef __attribute__((ext_vector_type(4))) float floatx4;

__device__ __forceinline__ unsigned short f2bf(float f) {
    unsigned int u = __float_as_uint(f);
    u = (u + 0x7fffu + ((u >> 16) & 1u)) >> 16;
    return (unsigned short)u;
}

__device__ __forceinline__ void gl_lds16(const void* g, void* l) {
    __builtin_amdgcn_global_load_lds((const __attribute__((address_space(1))) void*)g,
                                     (__attribute__((address_space(3))) void*)l, 16, 0, 0);
}

// ---------------------------------------------------------------- router ----
__global__ void router_kernel(const float* __restrict__ hidden,
                              const float* __restrict__ gate_w,
                              int* __restrict__ sel01, float* __restrict__ w01)
{
    int t = blockIdx.x;
    int lane = threadIdx.x;                      // 64 threads
    const float* hr = hidden + (size_t)t * Dm;
    float h[32];
#pragma unroll
    for (int i = 0; i < 32; ++i) h[i] = hr[lane + 64 * i];
    float logit[8];
#pragma unroll
    for (int e = 0; e < 8; ++e) {
        float acc = 0.f;
#pragma unroll
        for (int i = 0; i < 32; ++i) acc += h[i] * gate_w[(size_t)(lane + 64 * i) * 8 + e];
#pragma unroll
        for (int off = 1; off < 64; off <<= 1) acc += __shfl_xor(acc, off, 64);
        logit[e] = acc;
    }
    if (lane == 0) {
        int i0 = 0;
#pragma unroll
        for (int e = 1; e < 8; ++e) if (logit[e] > logit[i0]) i0 = e;
        int i1 = (i0 == 0) ? 1 : 0;
#pragma unroll
        for (int e = 0; e < 8; ++e) if (e != i0 && logit[e] > logit[i1]) i1 = e;
        float w0 = 1.f / (1.f + expf(logit[i1] - logit[i0]));
        sel01[2 * t] = i0; sel01[2 * t + 1] = i1;
        w01[2 * t] = w0;   w01[2 * t + 1] = 1.f - w0;
    }
}

// -------------------------------------------------------------- dispatch ----
// 1024 threads = 16 waves. Ballot-based scan, 3 barriers per expert.
__global__ void dispatch_kernel(const int* __restrict__ sel01,
                                int* __restrict__ list_c, int* __restrict__ posg,
                                int* __restrict__ cnt, int* __restrict__ basearr)
{
    __shared__ int wbase[16];
    __shared__ int sbase;
    int t = threadIdx.x;
    int lane = t & 63, w = t >> 6;
    int s0 = sel01[2 * t], s1 = sel01[2 * t + 1];
    if (t == 0) sbase = 0;
    __syncthreads();
    for (int e = 0; e < 8; ++e) {
        int flag  = (s0 == e || s1 == e) ? 1 : 0;
        int kslot = (s0 == e) ? 0 : 1;
        unsigned long long m = __ballot(flag);
        int lpre = __popcll(m & ((1ull << lane) - 1ull));
        if (lane == 0) wbase[w] = __popcll(m);
        __syncthreads();
        if (t == 0) {
            int run = sbase;
            basearr[e] = run;
            for (int i = 0; i < 16; ++i) { int tv = wbase[i]; wbase[i] = run; run += tv; }
            cnt[e] = run - sbase;
            sbase = run;
        }
        __syncthreads();
        if (flag) {
            int pos = wbase[w] + lpre;
            list_c[pos] = t;
            posg[2 * t + kslot] = pos;
        }
        __syncthreads();
    }
}

// ------------------------------------------------------------ bf16 casts ----
__global__ void cast_bf16_kernel(const float* __restrict__ x, unsigned short* __restrict__ y)
{
    int i = (blockIdx.x * 256 + threadIdx.x) * 4;
    float4 a = *(const float4*)(x + i);
    ushort4 o;
    o.x = f2bf(a.x); o.y = f2bf(a.y); o.z = f2bf(a.z); o.w = f2bf(a.w);
    *(ushort4*)(y + i) = o;
}

__global__ void gather_cast_kernel(const float* __restrict__ hidden, const int* __restrict__ list,
                                   unsigned short* __restrict__ xe)
{
    int slot = blockIdx.x;
    int tok = list[slot];
    const float* src = hidden + (size_t)tok * Dm;
    unsigned short* dst = xe + (size_t)slot * Dm;
    int c = threadIdx.x * 8;
    float4 a = *(const float4*)(src + c);
    float4 b = *(const float4*)(src + c + 4);
    ushort4 o1, o2;
    o1.x = f2bf(a.x); o1.y = f2bf(a.y); o1.z = f2bf(a.z); o1.w = f2bf(a.w);
    o2.x = f2bf(b.x); o2.y = f2bf(b.y); o2.z = f2bf(b.z); o2.w = f2bf(b.w);
    *(ushort4*)(dst + c) = o1;
    *(ushort4*)(dst + c + 4) = o2;
}

// fp32 [B][K][N] -> bf16 [B][N][K]
__global__ void transpose_cast_kernel(const float* __restrict__ in, unsigned short* __restrict__ out,
                                      int K, int N)
{
    __shared__ float tile[32][33];
    int b = blockIdx.z;
    int k0 = blockIdx.x * 32, n0 = blockIdx.y * 32;
    const float* ip = in + (size_t)b * K * N;
    unsigned short* op = out + (size_t)b * K * N;
    int tx = threadIdx.x & 31, ty = threadIdx.x >> 5;   // 32 x 8
#pragma unroll
    for (int i = 0; i < 4; ++i)
        tile[ty + i * 8][tx] = ip[(size_t)(k0 + ty + i * 8) * N + n0 + tx];
    __syncthreads();
#pragma unroll
    for (int i = 0; i < 4; ++i)
        op[(size_t)(n0 + ty + i * 8) * K + k0 + tx] = f2bf(tile[tx][ty + i * 8]);
}

// ----------------------------------------------------------- bf16 GEMM ------
// C[M][N] = A[M][K] * Bt[N][K]^T, 128x128 tile, BK=32, mfma 16x16x32 bf16.
// Depth-3 software pipeline, 4 LDS buffers (64 KiB), counted vmcnt fused into
// the barrier asm so hipcc cannot insert its own vmcnt(0) drain. Grids here
// are 96-384 blocks on 256 CUs (~1 wave/SIMD): no TLP hides the
// global_load_lds latency, the pipeline must. Depth-3 covers ~750 cyc of
// load latency vs ~250 cyc compute/iter (HBM ~900, L3 ~450).
template<bool EXPERT>
__global__ __launch_bounds__(256)
void gemm_bf16(const unsigned short* __restrict__ A,
               const unsigned short* __restrict__ Bt,
               float* __restrict__ C,
               const int* __restrict__ cnt, const int* __restrict__ basearr,
               int M, int K, int N)
{
    int e = EXPERT ? blockIdx.z : 0;
    int Mloc = M, base = 0;
    if (EXPERT) {
        Mloc = cnt[e]; base = basearr[e];
        if ((int)(blockIdx.x * 128) >= Mloc) return;
    }
    int m0 = blockIdx.x * 128, n0 = blockIdx.y * 128;
    const unsigned short* Ab = A + (size_t)base * K;
    const unsigned short* Bb = Bt + (size_t)e * (size_t)K * N;
    __shared__ unsigned short As[4][128 * 32];
    __shared__ unsigned short Bs[4][128 * 32];
    int tid = threadIdx.x;
    int lane = tid & 63, wave = tid >> 6;
    const unsigned short* ga[2];
    const unsigned short* gb[2];
    int lo[2];
#pragma unroll
    for (int j = 0; j < 2; ++j) {
        int flat = j * 256 + tid;
        int row = flat >> 2, sub = flat & 3;
        int ar = m0 + row; if (ar > Mloc - 1) ar = Mloc - 1;
        ga[j] = Ab + (size_t)ar * K + sub * 8;
        gb[j] = Bb + (size_t)(n0 + row) * K + sub * 8;
        lo[j] = flat * 8;
    }
    floatx4 acc[4][4];
#pragma unroll
    for (int i = 0; i < 4; ++i)
#pragma unroll
        for (int j = 0; j < 4; ++j) acc[i][j] = (floatx4){0.f, 0.f, 0.f, 0.f};

    int wm = (wave >> 1) * 64, wn = (wave & 1) * 64;
    int fr = lane & 15, kr = (lane >> 4) * 8;

    int nk = K >> 5;                       // K/32, >= 48 for all our shapes
    auto stage = [&](int buf, int t) {     // 4 VMEM instructions per wave
        int k0 = t << 5;
        gl_lds16(ga[0] + k0, As[buf] + lo[0]);
        gl_lds16(gb[0] + k0, Bs[buf] + lo[0]);
        gl_lds16(ga[1] + k0, As[buf] + lo[1]);
        gl_lds16(gb[1] + k0, Bs[buf] + lo[1]);
    };
    stage(0, 0);
    stage(1, 1);
    stage(2, 2);
    int cur = 0;
    for (int t = 0; t < nk; ++t) {
        int nxt = (cur + 3) & 3;
        if (t + 3 < nk) stage(nxt, t + 3);
        int ahead = nk - 1 - t;            // tiles in flight beyond t
        // wait: exactly tile t's 4 loads retired; up to 3 tiles stay in flight.
        if (ahead >= 3)      asm volatile("s_waitcnt vmcnt(12)\n\ts_barrier" ::: "memory");
        else if (ahead == 2) asm volatile("s_waitcnt vmcnt(8)\n\ts_barrier" ::: "memory");
        else if (ahead == 1) asm volatile("s_waitcnt vmcnt(4)\n\ts_barrier" ::: "memory");
        else                 asm volatile("s_waitcnt vmcnt(0)\n\ts_barrier" ::: "memory");
        bf16x8 af[4], bfr[4];
        const unsigned short* Ac = As[cur];
        const unsigned short* Bc = Bs[cur];
#pragma unroll
        for (int f = 0; f < 4; ++f) {
            af[f]  = *(const bf16x8*)(Ac + (size_t)(wm + f * 16 + fr) * 32 + kr);
            bfr[f] = *(const bf16x8*)(Bc + (size_t)(wn + f * 16 + fr) * 32 + kr);
        }
#pragma unroll
        for (int fm = 0; fm < 4; ++fm)
#pragma unroll
            for (int fn = 0; fn < 4; ++fn)
                acc[fm][fn] = __builtin_amdgcn_mfma_f32_16x16x32_bf16(af[fm], bfr[fn], acc[fm][fn], 0, 0, 0);
        // lgkmcnt(0): this wave's ds_reads must retire before crossing the
        // barrier -- buffer `cur` is restaged 3 iters later on the other side.
        asm volatile("s_waitcnt lgkmcnt(0)\n\ts_barrier" ::: "memory");
        cur = (cur + 1) & 3;
    }
    int rb = (lane >> 4) * 4;
#pragma unroll
    for (int fm = 0; fm < 4; ++fm) {
#pragma unroll
        for (int r = 0; r < 4; ++r) {
            int m = m0 + wm + fm * 16 + rb + r;
            if (m < Mloc) {
                float* cp = C + (size_t)(base + m) * N + n0 + wn + fr;
#pragma unroll
                for (int fn = 0; fn < 4; ++fn)
                    cp[fn * 16] = acc[fm][fn][r];
            }
        }
    }
}

// ------------------------------------------- beta / g small projections ----
__global__ void ba_kernel(const float* __restrict__ hidden,
                          const float* __restrict__ b_w, const float* __restrict__ a_w,
                          const float* __restrict__ A_log, const float* __restrict__ dt_bias,
                          const int* __restrict__ list, const int* __restrict__ cnt,
                          const int* __restrict__ basearr,
                          float* __restrict__ beta_c, float* __restrict__ g_c)
{
    int j = blockIdx.x, e = blockIdx.y;
    if (j >= cnt[e]) return;
    int gpos = basearr[e] + j;
    int tok = list[gpos];
    int lane = threadIdx.x;                      // 64
    const float* hr = hidden + (size_t)tok * Dm;
    float h[32];
#pragma unroll
    for (int i = 0; i < 32; ++i) h[i] = hr[lane + 64 * i];
    for (int c = 0; c < 12; ++c) {
        int col = c % 6;
        const float* W = ((c < 6) ? b_w : a_w) + (size_t)e * Dm * 6;
        float acc = 0.f;
#pragma unroll
        for (int i = 0; i < 32; ++i) acc += h[i] * W[(size_t)(lane + 64 * i) * 6 + col];
#pragma unroll
        for (int off = 1; off < 64; off <<= 1) acc += __shfl_xor(acc, off, 64);
        if (lane == 0) {
            if (c < 6) {
                beta_c[gpos * 6 + col] = 1.f / (1.f + expf(-acc));
            } else {
                float x = acc + dt_bias[col];
                float sp = (x > 20.f) ? x : log1pf(expf(x));
                g_c[gpos * 6 + col] = -expf(A_log[col]) * sp;
            }
        }
    }
}

// -------------------------------------- causal conv4 + silu (+ l2 norm) ----
template<bool GATHER>
__global__ void conv_norm_kernel(const float* __restrict__ X,
                                 const float* __restrict__ convw,
                                 const int* __restrict__ list, const int* __restrict__ cnt,
                                 const int* __restrict__ basearr,
                                 float* __restrict__ outb, float scale)
{
    int j = blockIdx.x, e = blockIdx.y, h = blockIdx.z;
    if (j >= cnt[e]) return;
    int base = basearr[e];
    int gpos = base + j;
    int c = h * DKk + threadIdx.x;               // 256 threads
    float acc = 0.f;
#pragma unroll
    for (int tau = 0; tau < 4; ++tau) {
        int jj = j - 3 + tau;
        if (jj >= 0) {
            const float* row = GATHER ? (X + (size_t)list[base + jj] * KD)
                                      : (X + (size_t)(base + jj) * KD);
            acc += row[c] * convw[c * 4 + tau];
        }
    }
    float y = acc / (1.f + expf(-acc));          // silu
    float v = y * y;
#pragma unroll
    for (int off = 1; off < 64; off <<= 1) v += __shfl_xor(v, off, 64);
    __shared__ float red[4];
    if ((threadIdx.x & 63) == 0) red[threadIdx.x >> 6] = v;
    __syncthreads();
    float total = red[0] + red[1] + red[2] + red[3];
    outb[(size_t)gpos * KD + c] = y * rsqrtf(total + 1e-6f) * scale;
}

__global__ void conv_v_kernel(const float* __restrict__ X,
                              const float* __restrict__ convw,
                              const int* __restrict__ cnt, const int* __restrict__ basearr,
                              float* __restrict__ outb)
{
    int j = blockIdx.x, e = blockIdx.y;
    if (j >= cnt[e]) return;
    int base = basearr[e];
    int gpos = base + j;
    int c = blockIdx.z * 256 + threadIdx.x;      // 12 * 256 = 3072
    float acc = 0.f;
#pragma unroll
    for (int tau = 0; tau < 4; ++tau) {
        int jj = j - 3 + tau;
        if (jj >= 0) acc += X[(size_t)(base + jj) * VD + c] * convw[c * 4 + tau];
    }
    outb[(size_t)gpos * VD + c] = acc / (1.f + expf(-acc));
}

// --------------------------------------------- gated delta rule (serial) ----
// grid (16, H, E); 256 threads; thread = (kpart 0..7, vcol 0..31), 32 state
// floats/thread. Ping-pong prefetch of next step's k/q/scalars; launch_bounds
// (256,2) caps VGPR at ~256 so nothing spills (R2 spilled at VGPR_Count=48).
__global__ __launch_bounds__(256, 2)
void recurrence_kernel(const float* __restrict__ qn, const float* __restrict__ kn,
                       const float* __restrict__ vc,
                       const float* __restrict__ beta_c, const float* __restrict__ g_c,
                       const int* __restrict__ cnt, const int* __restrict__ basearr,
                       float* __restrict__ o_c)
{
    int vb = blockIdx.x, h = blockIdx.y, e = blockIdx.z;
    int n = cnt[e], base = basearr[e];
    if (n <= 0) return;
    int kpart = threadIdx.x & 7;
    int vcol  = threadIdx.x >> 3;
    int v = vb * 32 + vcol;
    const float* kb = kn + (size_t)base * KD + h * DKk + kpart * 32;
    const float* qb = qn + (size_t)base * KD + h * DKk + kpart * 32;
    const float* vp = vc + (size_t)base * VD + h * DVv + v;
    const float* gp = g_c + (size_t)base * Hh + h;
    const float* bp = beta_c + (size_t)base * Hh + h;
    float* op = o_c + (size_t)base * VD + h * DVv + v;
    float4 s[8];
#pragma unroll
    for (int i = 0; i < 8; ++i) s[i] = make_float4(0.f, 0.f, 0.f, 0.f);

    float4 kA[8], qA[8], kB[8], qB[8];
    float gA, bA, vA, gB, bB, vB;

#define LOADSTEP(K_, Q_, G_, B_, V_, jj) do {                                  \
        const float4* krp_ = (const float4*)(kb + (size_t)(jj) * KD);          \
        const float4* qrp_ = (const float4*)(qb + (size_t)(jj) * KD);          \
        _Pragma("unroll") for (int i_ = 0; i_ < 8; ++i_) {                     \
            K_[i_] = krp_[i_]; Q_[i_] = qrp_[i_]; }                            \
        G_ = gp[(size_t)(jj) * Hh]; B_ = bp[(size_t)(jj) * Hh];                \
        V_ = vp[(size_t)(jj) * VD];                                            \
    } while (0)

    auto compute = [&](const float4 (&kk)[8], const float4 (&qq)[8],
                       float gv, float btv, float vval, int j) {
        float4 pa = make_float4(0.f, 0.f, 0.f, 0.f);
        float4 ra = make_float4(0.f, 0.f, 0.f, 0.f);
        float4 qa = make_float4(0.f, 0.f, 0.f, 0.f);
#pragma unroll
        for (int i = 0; i < 8; ++i) {
            pa.x = fmaf(kk[i].x, s[i].x, pa.x); pa.y = fmaf(kk[i].y, s[i].y, pa.y);
            pa.z = fmaf(kk[i].z, s[i].z, pa.z); pa.w = fmaf(kk[i].w, s[i].w, pa.w);
            ra.x = fmaf(qq[i].x, s[i].x, ra.x); ra.y = fmaf(qq[i].y, s[i].y, ra.y);
            ra.z = fmaf(qq[i].z, s[i].z, ra.z); ra.w = fmaf(qq[i].w, s[i].w, ra.w);
            qa.x = fmaf(qq[i].x, kk[i].x, qa.x); qa.y = fmaf(qq[i].y, kk[i].y, qa.y);
            qa.z = fmaf(qq[i].z, kk[i].z, qa.z); qa.w = fmaf(qq[i].w, kk[i].w, qa.w);
        }
        float p  = (pa.x + pa.y) + (pa.z + pa.w);
        float r  = (ra.x + ra.y) + (ra.z + ra.w);
        float qk = (qa.x + qa.y) + (qa.z + qa.w);
#pragma unroll
        for (int m = 1; m < 8; m <<= 1) {
            p  += __shfl_xor(p,  m, 64);
            r  += __shfl_xor(r,  m, 64);
            qk += __shfl_xor(qk, m, 64);
        }
        float eg = __expf(gv);
        float delta = (vval - p * eg) * btv;
        float out = fmaf(qk, delta, eg * r);
#pragma unroll
        for (int i = 0; i < 8; ++i) {
            s[i].x = fmaf(eg, s[i].x, kk[i].x * delta);
            s[i].y = fmaf(eg, s[i].y, kk[i].y * delta);
            s[i].z = fmaf(eg, s[i].z, kk[i].z * delta);
            s[i].w = fmaf(eg, s[i].w, kk[i].w * delta);
        }
        if (kpart == 0) op[(size_t)j * VD] = out;
    };

    LOADSTEP(kA, qA, gA, bA, vA, 0);
    for (int j = 0; j < n; j += 2) {
        if (j + 1 < n) LOADSTEP(kB, qB, gB, bB, vB, j + 1);
        compute(kA, qA, gA, bA, vA, j);
        if (j + 1 >= n) break;
        if (j + 2 < n) LOADSTEP(kA, qA, gA, bA, vA, j + 2);
        compute(kB, qB, gB, bB, vB, j + 1);
    }
#undef LOADSTEP
}

// ------------------------------- combine + gated RMSNorm (swish gate) -------
__global__ void combine_kernel(const float* __restrict__ o_c, const float* __restrict__ gg,
                               const float* __restrict__ norm_w,
                               const int* __restrict__ posg, const float* __restrict__ w01,
                               unsigned short* __restrict__ ocg)
{
    int t = blockIdx.x, h = blockIdx.y;
    int p0 = posg[2 * t], p1 = posg[2 * t + 1];
    float w0 = w01[2 * t], w1 = w01[2 * t + 1];
    int v0 = threadIdx.x, v1 = threadIdx.x + 256;
    size_t r0 = (size_t)p0 * VD + h * DVv, r1 = (size_t)p1 * VD + h * DVv;
    float a  = w0 * o_c[r0 + v0] + w1 * o_c[r1 + v0];
    float b2 = w0 * o_c[r0 + v1] + w1 * o_c[r1 + v1];
    float val = a * a + b2 * b2;
#pragma unroll
    for (int off = 1; off < 64; off <<= 1) val += __shfl_xor(val, off, 64);
    __shared__ float red[4];
    if ((threadIdx.x & 63) == 0) red[threadIdx.x >> 6] = val;
    __syncthreads();
    float total = red[0] + red[1] + red[2] + red[3];
    float rms = rsqrtf(total / 512.f + 1e-5f);
    size_t og = (size_t)t * VD + h * DVv;
    float g0 = gg[og + v0], g1 = gg[og + v1];
    ocg[og + v0] = f2bf(a  * rms * norm_w[v0] * g0 / (1.f + expf(-g0)));
    ocg[og + v1] = f2bf(b2 * rms * norm_w[v1] * g1 / (1.f + expf(-g1)));
}

// ------------------------------------------------------------------ host ----
extern "C" void kernel_launch(void* const* d_in, const int* in_sizes, int n_in,
                              void* d_out, int out_size, void* d_ws, size_t ws_size,
                              hipStream_t stream)
{
    const float* hidden   = (const float*)d_in[0];
    const float* q_w      = (const float*)d_in[1];
    const float* gate_w   = (const float*)d_in[2];
    const float* k_w      = (const float*)d_in[3];
    const float* v_w      = (const float*)d_in[4];
    const float* b_w      = (const float*)d_in[5];
    const float* a_w      = (const float*)d_in[6];
    const float* A_log    = (const float*)d_in[7];
    const float* dt_bias  = (const float*)d_in[8];
    const float* q_conv_w = (const float*)d_in[9];
    const float* k_conv_w = (const float*)d_in[10];
    const float* v_conv_w = (const float*)d_in[11];
    const float* g_w      = (const float*)d_in[12];
    const float* norm_w   = (const float*)d_in[13];
    const float* o_w      = (const float*)d_in[14];
    float* outp = (float*)d_out;

    float* f = (float*)d_ws;
    size_t off = 0;
    auto alloc = [&](size_t n) { float* p = f + off; off += (n + 3) & ~(size_t)3; return p; };
    float* qh     = alloc((size_t)1024 * 1536);
    float* kraw   = alloc((size_t)2048 * 1536);
    float* qn     = alloc((size_t)2048 * 1536);
    float* kn     = alloc((size_t)2048 * 1536);
    float* vraw   = alloc((size_t)2048 * 3072);   // reused as o_c after conv_v
    float* vconv  = alloc((size_t)2048 * 3072);
    float* gg     = alloc((size_t)1024 * 3072);
    float* beta_c = alloc(2048 * 6);
    float* g_c    = alloc(2048 * 6);
    float* w01f   = alloc(2048);

    unsigned short* u = (unsigned short*)(f + off);
    size_t uoff = 0;
    auto ualloc = [&](size_t n) { unsigned short* p = u + uoff; uoff += (n + 7) & ~(size_t)7; return p; };
    unsigned short* hidden_bf = ualloc((size_t)1024 * 2048);
    unsigned short* xe_c      = ualloc((size_t)2048 * 2048);
    unsigned short* ocg       = ualloc((size_t)1024 * 3072);
    unsigned short* q_wT      = ualloc((size_t)2048 * 1536);
    unsigned short* k_wT      = ualloc((size_t)8 * 2048 * 1536);
    unsigned short* v_wT      = ualloc((size_t)8 * 2048 * 3072);
    unsigned short* g_wT      = ualloc((size_t)2048 * 3072);
    unsigned short* o_wT      = ualloc((size_t)3072 * 2048);

    int* ib      = (int*)(u + uoff);
    int* sel01   = ib;
    int* list_c  = ib + 2048;
    int* posg    = ib + 4096;
    int* cnt     = ib + 6144;
    int* basearr = ib + 6152;
    float* o_c = vraw;

    router_kernel<<<1024, 64, 0, stream>>>(hidden, gate_w, sel01, w01f);
    dispatch_kernel<<<1, 1024, 0, stream>>>(sel01, list_c, posg, cnt, basearr);

    cast_bf16_kernel<<<2048, 256, 0, stream>>>(hidden, hidden_bf);
    gather_cast_kernel<<<2048, 256, 0, stream>>>(hidden, list_c, xe_c);
    transpose_cast_kernel<<<dim3(64, 48, 1), 256, 0, stream>>>(q_w, q_wT, 2048, 1536);
    transpose_cast_kernel<<<dim3(64, 48, 8), 256, 0, stream>>>(k_w, k_wT, 2048, 1536);
    transpose_cast_kernel<<<dim3(64, 96, 8), 256, 0, stream>>>(v_w, v_wT, 2048, 3072);
    transpose_cast_kernel<<<dim3(64, 96, 1), 256, 0, stream>>>(g_w, g_wT, 2048, 3072);
    transpose_cast_kernel<<<dim3(96, 64, 1), 256, 0, stream>>>(o_w, o_wT, 3072, 2048);

    gemm_bf16<false><<<dim3(8, 12), 256, 0, stream>>>(hidden_bf, q_wT, qh, nullptr, nullptr, 1024, 2048, 1536);
    gemm_bf16<true ><<<dim3(8, 12, 8), 256, 0, stream>>>(xe_c, k_wT, kraw, cnt, basearr, 0, 2048, 1536);
    gemm_bf16<true ><<<dim3(8, 24, 8), 256, 0, stream>>>(xe_c, v_wT, vraw, cnt, basearr, 0, 2048, 3072);
    gemm_bf16<false><<<dim3(8, 24), 256, 0, stream>>>(hidden_bf, g_wT, gg, nullptr, nullptr, 1024, 2048, 3072);

    ba_kernel<<<dim3(1024, 8), 64, 0, stream>>>(hidden, b_w, a_w, A_log, dt_bias,
                                                list_c, cnt, basearr, beta_c, g_c);

    conv_norm_kernel<true ><<<dim3(1024, 8, 6), 256, 0, stream>>>(qh,   q_conv_w, list_c, cnt, basearr, qn, 0.0625f);
    conv_norm_kernel<false><<<dim3(1024, 8, 6), 256, 0, stream>>>(kraw, k_conv_w, list_c, cnt, basearr, kn, 1.0f);
    conv_v_kernel<<<dim3(1024, 8, 12), 256, 0, stream>>>(vraw, v_conv_w, cnt, basearr, vconv);

    recurrence_kernel<<<dim3(16, 6, 8), 256, 0, stream>>>(qn, kn, vconv, beta_c, g_c,
                                                          cnt, basearr, o_c);

    combine_kernel<<<dim3(1024, 6), 256, 0, stream>>>(o_c, gg, norm_w, posg, w01f, ocg);
    gemm_bf16<false><<<dim3(8, 16), 256, 0, stream>>>(ocg, o_wT, outp, nullptr, nullptr, 1024, 3072, 2048);
}

// Round 5
// 1286.413 us; speedup vs baseline: 1.8785x; 1.8785x over previous
//
#include <hip/hip_runtime.h>
#include <math.h>

#define Dm    2048
#define Hh    6
#define DKk   256
#define DVv   512
#define KD    1536
#define VD    3072
#define CH    4

typedef __attribute__((ext_vector_type(8))) __bf16 bf16x8;
typedef __attribute__((ext_vector_type(4))) float floatx4;

__device__ __forceinline__ unsigned short f2bf(float f) {
    unsigned int u = __float_as_uint(f);
    u = (u + 0x7fffu + ((u >> 16) & 1u)) >> 16;
    return (unsigned short)u;
}

__device__ __forceinline__ void gl_lds16(const void* g, void* l) {
    __builtin_amdgcn_global_load_lds((const __attribute__((address_space(1))) void*)g,
                                     (__attribute__((address_space(3))) void*)l, 16, 0, 0);
}

// ---------------------------------------------------------------- router ----
__global__ void router_kernel(const float* __restrict__ hidden,
                              const float* __restrict__ gate_w,
                              int* __restrict__ sel01, float* __restrict__ w01)
{
    int t = blockIdx.x;
    int lane = threadIdx.x;                      // 64 threads
    const float* hr = hidden + (size_t)t * Dm;
    float h[32];
#pragma unroll
    for (int i = 0; i < 32; ++i) h[i] = hr[lane + 64 * i];
    float logit[8];
#pragma unroll
    for (int e = 0; e < 8; ++e) {
        float acc = 0.f;
#pragma unroll
        for (int i = 0; i < 32; ++i) acc += h[i] * gate_w[(size_t)(lane + 64 * i) * 8 + e];
#pragma unroll
        for (int off = 1; off < 64; off <<= 1) acc += __shfl_xor(acc, off, 64);
        logit[e] = acc;
    }
    if (lane == 0) {
        int i0 = 0;
#pragma unroll
        for (int e = 1; e < 8; ++e) if (logit[e] > logit[i0]) i0 = e;
        int i1 = (i0 == 0) ? 1 : 0;
#pragma unroll
        for (int e = 0; e < 8; ++e) if (e != i0 && logit[e] > logit[i1]) i1 = e;
        float w0 = 1.f / (1.f + expf(logit[i1] - logit[i0]));
        sel01[2 * t] = i0; sel01[2 * t + 1] = i1;
        w01[2 * t] = w0;   w01[2 * t + 1] = 1.f - w0;
    }
}

// -------------------------------------------------------------- dispatch ----
__global__ void dispatch_kernel(const int* __restrict__ sel01,
                                int* __restrict__ list_c, int* __restrict__ posg,
                                int* __restrict__ cnt, int* __restrict__ basearr)
{
    __shared__ int wbase[16];
    __shared__ int sbase;
    int t = threadIdx.x;
    int lane = t & 63, w = t >> 6;
    int s0 = sel01[2 * t], s1 = sel01[2 * t + 1];
    if (t == 0) sbase = 0;
    __syncthreads();
    for (int e = 0; e < 8; ++e) {
        int flag  = (s0 == e || s1 == e) ? 1 : 0;
        int kslot = (s0 == e) ? 0 : 1;
        unsigned long long m = __ballot(flag);
        int lpre = __popcll(m & ((1ull << lane) - 1ull));
        if (lane == 0) wbase[w] = __popcll(m);
        __syncthreads();
        if (t == 0) {
            int run = sbase;
            basearr[e] = run;
            for (int i = 0; i < 16; ++i) { int tv = wbase[i]; wbase[i] = run; run += tv; }
            cnt[e] = run - sbase;
            sbase = run;
        }
        __syncthreads();
        if (flag) {
            int pos = wbase[w] + lpre;
            list_c[pos] = t;
            posg[2 * t + kslot] = pos;
        }
        __syncthreads();
    }
}

// ------------------------------------------------------------ bf16 casts ----
__global__ void cast_bf16_kernel(const float* __restrict__ x, unsigned short* __restrict__ y)
{
    int i = (blockIdx.x * 256 + threadIdx.x) * 4;
    float4 a = *(const float4*)(x + i);
    ushort4 o;
    o.x = f2bf(a.x); o.y = f2bf(a.y); o.z = f2bf(a.z); o.w = f2bf(a.w);
    *(ushort4*)(y + i) = o;
}

__global__ void gather_cast_kernel(const float* __restrict__ hidden, const int* __restrict__ list,
                                   unsigned short* __restrict__ xe)
{
    int slot = blockIdx.x;
    int tok = list[slot];
    const float* src = hidden + (size_t)tok * Dm;
    unsigned short* dst = xe + (size_t)slot * Dm;
    int c = threadIdx.x * 8;
    float4 a = *(const float4*)(src + c);
    float4 b = *(const float4*)(src + c + 4);
    ushort4 o1, o2;
    o1.x = f2bf(a.x); o1.y = f2bf(a.y); o1.z = f2bf(a.z); o1.w = f2bf(a.w);
    o2.x = f2bf(b.x); o2.y = f2bf(b.y); o2.z = f2bf(b.z); o2.w = f2bf(b.w);
    *(ushort4*)(dst + c) = o1;
    *(ushort4*)(dst + c + 4) = o2;
}

// fp32 [B][K][N] -> bf16 [B][N][K]
__global__ void transpose_cast_kernel(const float* __restrict__ in, unsigned short* __restrict__ out,
                                      int K, int N)
{
    __shared__ float tile[32][33];
    int b = blockIdx.z;
    int k0 = blockIdx.x * 32, n0 = blockIdx.y * 32;
    const float* ip = in + (size_t)b * K * N;
    unsigned short* op = out + (size_t)b * K * N;
    int tx = threadIdx.x & 31, ty = threadIdx.x >> 5;   // 32 x 8
#pragma unroll
    for (int i = 0; i < 4; ++i)
        tile[ty + i * 8][tx] = ip[(size_t)(k0 + ty + i * 8) * N + n0 + tx];
    __syncthreads();
#pragma unroll
    for (int i = 0; i < 4; ++i)
        op[(size_t)(n0 + ty + i * 8) * K + k0 + tx] = f2bf(tile[tx][ty + i * 8]);
}

// ----------------------------------------------------------- bf16 GEMM ------
// C[M][N] = A[M][K] * Bt[N][K]^T, 128x128 tile, BK=32, mfma 16x16x32 bf16.
// Depth-3 software pipeline, 4 LDS buffers, counted vmcnt fused into the
// barrier asm so hipcc cannot insert its own vmcnt(0) drain.
template<bool EXPERT>
__global__ __launch_bounds__(256)
void gemm_bf16(const unsigned short* __restrict__ A,
               const unsigned short* __restrict__ Bt,
               float* __restrict__ C,
               const int* __restrict__ cnt, const int* __restrict__ basearr,
               int M, int K, int N)
{
    int e = EXPERT ? blockIdx.z : 0;
    int Mloc = M, base = 0;
    if (EXPERT) {
        Mloc = cnt[e]; base = basearr[e];
        if ((int)(blockIdx.x * 128) >= Mloc) return;
    }
    int m0 = blockIdx.x * 128, n0 = blockIdx.y * 128;
    const unsigned short* Ab = A + (size_t)base * K;
    const unsigned short* Bb = Bt + (size_t)e * (size_t)K * N;
    __shared__ unsigned short As[4][128 * 32];
    __shared__ unsigned short Bs[4][128 * 32];
    int tid = threadIdx.x;
    int lane = tid & 63, wave = tid >> 6;
    const unsigned short* ga[2];
    const unsigned short* gb[2];
    int lo[2];
#pragma unroll
    for (int j = 0; j < 2; ++j) {
        int flat = j * 256 + tid;
        int row = flat >> 2, sub = flat & 3;
        int ar = m0 + row; if (ar > Mloc - 1) ar = Mloc - 1;
        ga[j] = Ab + (size_t)ar * K + sub * 8;
        gb[j] = Bb + (size_t)(n0 + row) * K + sub * 8;
        lo[j] = flat * 8;
    }
    floatx4 acc[4][4];
#pragma unroll
    for (int i = 0; i < 4; ++i)
#pragma unroll
        for (int j = 0; j < 4; ++j) acc[i][j] = (floatx4){0.f, 0.f, 0.f, 0.f};

    int wm = (wave >> 1) * 64, wn = (wave & 1) * 64;
    int fr = lane & 15, kr = (lane >> 4) * 8;

    int nk = K >> 5;
    auto stage = [&](int buf, int t) {
        int k0 = t << 5;
        gl_lds16(ga[0] + k0, As[buf] + lo[0]);
        gl_lds16(gb[0] + k0, Bs[buf] + lo[0]);
        gl_lds16(ga[1] + k0, As[buf] + lo[1]);
        gl_lds16(gb[1] + k0, Bs[buf] + lo[1]);
    };
    stage(0, 0);
    stage(1, 1);
    stage(2, 2);
    int cur = 0;
    for (int t = 0; t < nk; ++t) {
        int nxt = (cur + 3) & 3;
        if (t + 3 < nk) stage(nxt, t + 3);
        int ahead = nk - 1 - t;
        if (ahead >= 3)      asm volatile("s_waitcnt vmcnt(12)\n\ts_barrier" ::: "memory");
        else if (ahead == 2) asm volatile("s_waitcnt vmcnt(8)\n\ts_barrier" ::: "memory");
        else if (ahead == 1) asm volatile("s_waitcnt vmcnt(4)\n\ts_barrier" ::: "memory");
        else                 asm volatile("s_waitcnt vmcnt(0)\n\ts_barrier" ::: "memory");
        bf16x8 af[4], bfr[4];
        const unsigned short* Ac = As[cur];
        const unsigned short* Bc = Bs[cur];
#pragma unroll
        for (int f = 0; f < 4; ++f) {
            af[f]  = *(const bf16x8*)(Ac + (size_t)(wm + f * 16 + fr) * 32 + kr);
            bfr[f] = *(const bf16x8*)(Bc + (size_t)(wn + f * 16 + fr) * 32 + kr);
        }
#pragma unroll
        for (int fm = 0; fm < 4; ++fm)
#pragma unroll
            for (int fn = 0; fn < 4; ++fn)
                acc[fm][fn] = __builtin_amdgcn_mfma_f32_16x16x32_bf16(af[fm], bfr[fn], acc[fm][fn], 0, 0, 0);
        asm volatile("s_waitcnt lgkmcnt(0)\n\ts_barrier" ::: "memory");
        cur = (cur + 1) & 3;
    }
    int rb = (lane >> 4) * 4;
#pragma unroll
    for (int fm = 0; fm < 4; ++fm) {
#pragma unroll
        for (int r = 0; r < 4; ++r) {
            int m = m0 + wm + fm * 16 + rb + r;
            if (m < Mloc) {
                float* cp = C + (size_t)(base + m) * N + n0 + wn + fr;
#pragma unroll
                for (int fn = 0; fn < 4; ++fn)
                    cp[fn * 16] = acc[fm][fn][r];
            }
        }
    }
}

// ------------------------------------------- beta / g small projections ----
__global__ void ba_kernel(const float* __restrict__ hidden,
                          const float* __restrict__ b_w, const float* __restrict__ a_w,
                          const float* __restrict__ A_log, const float* __restrict__ dt_bias,
                          const int* __restrict__ list, const int* __restrict__ cnt,
                          const int* __restrict__ basearr,
                          float* __restrict__ beta_c, float* __restrict__ g_c)
{
    int j = blockIdx.x, e = blockIdx.y;
    if (j >= cnt[e]) return;
    int gpos = basearr[e] + j;
    int tok = list[gpos];
    int lane = threadIdx.x;                      // 64
    const float* hr = hidden + (size_t)tok * Dm;
    float h[32];
#pragma unroll
    for (int i = 0; i < 32; ++i) h[i] = hr[lane + 64 * i];
    for (int c = 0; c < 12; ++c) {
        int col = c % 6;
        const float* W = ((c < 6) ? b_w : a_w) + (size_t)e * Dm * 6;
        float acc = 0.f;
#pragma unroll
        for (int i = 0; i < 32; ++i) acc += h[i] * W[(size_t)(lane + 64 * i) * 6 + col];
#pragma unroll
        for (int off = 1; off < 64; off <<= 1) acc += __shfl_xor(acc, off, 64);
        if (lane == 0) {
            if (c < 6) {
                beta_c[gpos * 6 + col] = 1.f / (1.f + expf(-acc));
            } else {
                float x = acc + dt_bias[col];
                float sp = (x > 20.f) ? x : log1pf(expf(x));
                g_c[gpos * 6 + col] = -expf(A_log[col]) * sp;
            }
        }
    }
}

// -------------------------------------- causal conv4 + silu (+ l2 norm) ----
template<bool GATHER>
__global__ void conv_norm_kernel(const float* __restrict__ X,
                                 const float* __restrict__ convw,
                                 const int* __restrict__ list, const int* __restrict__ cnt,
                                 const int* __restrict__ basearr,
                                 float* __restrict__ outb, float scale)
{
    int j = blockIdx.x, e = blockIdx.y, h = blockIdx.z;
    if (j >= cnt[e]) return;
    int base = basearr[e];
    int gpos = base + j;
    int c = h * DKk + threadIdx.x;               // 256 threads
    float acc = 0.f;
#pragma unroll
    for (int tau = 0; tau < 4; ++tau) {
        int jj = j - 3 + tau;
        if (jj >= 0) {
            const float* row = GATHER ? (X + (size_t)list[base + jj] * KD)
                                      : (X + (size_t)(base + jj) * KD);
            acc += row[c] * convw[c * 4 + tau];
        }
    }
    float y = acc / (1.f + expf(-acc));          // silu
    float v = y * y;
#pragma unroll
    for (int off = 1; off < 64; off <<= 1) v += __shfl_xor(v, off, 64);
    __shared__ float red[4];
    if ((threadIdx.x & 63) == 0) red[threadIdx.x >> 6] = v;
    __syncthreads();
    float total = red[0] + red[1] + red[2] + red[3];
    outb[(size_t)gpos * KD + c] = y * rsqrtf(total + 1e-6f) * scale;
}

__global__ void conv_v_kernel(const float* __restrict__ X,
                              const float* __restrict__ convw,
                              const int* __restrict__ cnt, const int* __restrict__ basearr,
                              float* __restrict__ outb)
{
    int j = blockIdx.x, e = blockIdx.y;
    if (j >= cnt[e]) return;
    int base = basearr[e];
    int gpos = base + j;
    int c = blockIdx.z * 256 + threadIdx.x;      // 12 * 256 = 3072
    float acc = 0.f;
#pragma unroll
    for (int tau = 0; tau < 4; ++tau) {
        int jj = j - 3 + tau;
        if (jj >= 0) acc += X[(size_t)(base + jj) * VD + c] * convw[c * 4 + tau];
    }
    outb[(size_t)gpos * VD + c] = acc / (1.f + expf(-acc));
}

// ------------------------------------------------ qk = q . k precompute ----
// qk_t = q_t . k_t per (slot, head): state-independent, hoisted out of the
// serial recurrence (it was recomputed by 512 threads per (e,h,t)).
__global__ void qk_kernel(const float* __restrict__ qn, const float* __restrict__ kn,
                          float* __restrict__ qk_c)
{
    int gpos = blockIdx.x, h = blockIdx.y;
    int lane = threadIdx.x;                      // 64
    const float4* qp = (const float4*)(qn + (size_t)gpos * KD + h * DKk);
    const float4* kp = (const float4*)(kn + (size_t)gpos * KD + h * DKk);
    float4 a = qp[lane], b = kp[lane];
    float acc = a.x * b.x + a.y * b.y + a.z * b.z + a.w * b.w;
#pragma unroll
    for (int off = 1; off < 64; off <<= 1) acc += __shfl_xor(acc, off, 64);
    if (lane == 0) qk_c[(size_t)gpos * Hh + h] = acc;
}

// --------------------------------------------- gated delta rule (serial) ----
// grid (16, H, E); 256 threads = 4 waves; thread = (kpart 0..7, vcol 0..31).
// R3/R4 rewrite: the old reg ping-pong (128 VGPRs of k/q) spilled to scratch
// (VGPR_Count=104) -> serialized scratch round-trips in the dependency chain
// (1411 us, VALUBusy 17%, HBM 1.2%). Now: k/q staged in LDS via gl_lds16
// (double-buffered CH=4-step chunks, counted vmcnt(2), shared by 4 waves),
// scalars chunk-prefetched in regs (static indexing), qk hoisted.
// R4: (a) bank-conflict-free k-slice: lane reads float4 at kpart*4 + i*32
// (banks kpart*4..kpart*4+3 per read -> all 32 banks; the old kpart*32
// layout put all 8 kparts on the same 4 banks = 8-way conflict). The
// dim->thread ownership is internal (shfl reduces over all kparts).
// (b) launch_bounds(256,3): 768 blocks = 3 blocks/CU single pass; VGPR cap
// ~170 leaves headroom (cap 128 at ",4" risked re-spilling).
__global__ __launch_bounds__(256, 3)
void recurrence_kernel(const float* __restrict__ qn, const float* __restrict__ kn,
                       const float* __restrict__ vc,
                       const float* __restrict__ beta_c, const float* __restrict__ g_c,
                       const float* __restrict__ qk_c,
                       const int* __restrict__ cnt, const int* __restrict__ basearr,
                       float* __restrict__ o_c)
{
    int vb = blockIdx.x, h = blockIdx.y, e = blockIdx.z;
    int n = cnt[e], base = basearr[e];
    if (n <= 0) return;
    int tid = threadIdx.x;
    int kpart = tid & 7, vcol = tid >> 3;
    int v = vb * 32 + vcol;
    int wv = tid >> 6, lane = tid & 63;

    __shared__ float lk[2][CH][256];             // 8 KB
    __shared__ float lq[2][CH][256];             // 8 KB

    const float* kb = kn + (size_t)base * KD + h * DKk;
    const float* qb = qn + (size_t)base * KD + h * DKk;
    const float* vp = vc + (size_t)base * VD + h * DVv + v;
    const float* gp = g_c    + (size_t)base * Hh + h;
    const float* bp = beta_c + (size_t)base * Hh + h;
    const float* xp = qk_c   + (size_t)base * Hh + h;
    float* op = o_c + (size_t)base * VD + h * DVv + v;

    float4 s[8];
#pragma unroll
    for (int i = 0; i < 8; ++i) s[i] = make_float4(0.f, 0.f, 0.f, 0.f);

    int nch = (n + CH - 1) / CH;

    // wave wv stages row wv of the chunk: 1 k-row + 1 q-row = 2 vm insts/wave.
    // LDS dest is linear base+lane*16 (gl_lds16 requirement); rows clamped.
    auto stageKQ = [&](int buf, int c) {
        int jj = c * CH + wv; if (jj > n - 1) jj = n - 1;
        gl_lds16(kb + (size_t)jj * KD + lane * 4, &lk[buf][wv][lane * 4]);
        gl_lds16(qb + (size_t)jj * KD + lane * 4, &lq[buf][wv][lane * 4]);
    };

    float vA[CH], gA[CH], bA[CH], xA[CH];
    float vB[CH], gB[CH], bB[CH], xB[CH];

    auto loadScal = [&](float (&V)[CH], float (&G)[CH], float (&B)[CH], float (&X)[CH], int c) {
#pragma unroll
        for (int u = 0; u < CH; ++u) {
            int jj = c * CH + u; if (jj > n - 1) jj = n - 1;
            V[u] = vp[(size_t)jj * VD];
            G[u] = gp[(size_t)jj * Hh];
            B[u] = bp[(size_t)jj * Hh];
            X[u] = xp[(size_t)jj * Hh];
        }
    };

    auto computeChunk = [&](const float (&Lk)[CH][256], const float (&Lq)[CH][256],
                            const float (&V)[CH], const float (&G)[CH],
                            const float (&B)[CH], const float (&X)[CH], int c) {
#pragma unroll
        for (int u = 0; u < CH; ++u) {
            // lane owns k-dims {kpart*4 + i*32 + j}: conflict-free banks.
            const float* Lku = &Lk[u][kpart * 4];
            const float* Lqu = &Lq[u][kpart * 4];
            float4 pa0 = make_float4(0.f,0.f,0.f,0.f), pa1 = make_float4(0.f,0.f,0.f,0.f);
            float4 ra0 = make_float4(0.f,0.f,0.f,0.f), ra1 = make_float4(0.f,0.f,0.f,0.f);
            float4 kk[8];
#pragma unroll
            for (int i = 0; i < 8; ++i) {
                kk[i] = *(const float4*)(Lku + i * 32);
                float4 qq = *(const float4*)(Lqu + i * 32);
                float4& pa = (i & 1) ? pa1 : pa0;
                float4& ra = (i & 1) ? ra1 : ra0;
                pa.x = fmaf(kk[i].x, s[i].x, pa.x); pa.y = fmaf(kk[i].y, s[i].y, pa.y);
                pa.z = fmaf(kk[i].z, s[i].z, pa.z); pa.w = fmaf(kk[i].w, s[i].w, pa.w);
                ra.x = fmaf(qq.x, s[i].x, ra.x); ra.y = fmaf(qq.y, s[i].y, ra.y);
                ra.z = fmaf(qq.z, s[i].z, ra.z); ra.w = fmaf(qq.w, s[i].w, ra.w);
            }
            float p = ((pa0.x + pa1.x) + (pa0.y + pa1.y)) + ((pa0.z + pa1.z) + (pa0.w + pa1.w));
            float r = ((ra0.x + ra1.x) + (ra0.y + ra1.y)) + ((ra0.z + ra1.z) + (ra0.w + ra1.w));
#pragma unroll
            for (int m = 1; m < 8; m <<= 1) {
                p += __shfl_xor(p, m, 64);
                r += __shfl_xor(r, m, 64);
            }
            float eg = __expf(G[u]);
            float delta = (V[u] - p * eg) * B[u];
            float out = fmaf(X[u], delta, eg * r);
#pragma unroll
            for (int i = 0; i < 8; ++i) {
                s[i].x = fmaf(eg, s[i].x, kk[i].x * delta);
                s[i].y = fmaf(eg, s[i].y, kk[i].y * delta);
                s[i].z = fmaf(eg, s[i].z, kk[i].z * delta);
                s[i].w = fmaf(eg, s[i].w, kk[i].w * delta);
            }
            int j = c * CH + u;
            if (kpart == 0 && j < n) op[(size_t)j * VD] = out;
        }
    };

    // prologue: chunk0 kq + scalars, chunk1 kq in flight.
    stageKQ(0, 0);
    loadScal(vA, gA, bA, xA, 0);
    stageKQ(1, 1);
    asm volatile("s_waitcnt vmcnt(2)\n\ts_barrier" ::: "memory");

    for (int c = 0; c < nch; c += 2) {
        loadScal(vB, gB, bB, xB, c + 1);         // clamped; uniform vm counts
        computeChunk(lk[0], lq[0], vA, gA, bA, xA, c);
        __syncthreads();                          // all waves done reading lk[0]
        stageKQ(0, c + 2);                        // clamped (always 2 insts)
        asm volatile("s_waitcnt vmcnt(2)\n\ts_barrier" ::: "memory");
        if (c + 1 >= nch) break;
        loadScal(vA, gA, bA, xA, c + 2);
        computeChunk(lk[1], lq[1], vB, gB, bB, xB, c + 1);
        __syncthreads();
        stageKQ(1, c + 3);
        asm volatile("s_waitcnt vmcnt(2)\n\ts_barrier" ::: "memory");
    }
    asm volatile("s_waitcnt vmcnt(0)" ::: "memory");   // drain tail staging
}

// ------------------------------- combine + gated RMSNorm (swish gate) -------
__global__ void combine_kernel(const float* __restrict__ o_c, const float* __restrict__ gg,
                               const float* __restrict__ norm_w,
                               const int* __restrict__ posg, const float* __restrict__ w01,
                               unsigned short* __restrict__ ocg)
{
    int t = blockIdx.x, h = blockIdx.y;
    int p0 = posg[2 * t], p1 = posg[2 * t + 1];
    float w0 = w01[2 * t], w1 = w01[2 * t + 1];
    int v0 = threadIdx.x, v1 = threadIdx.x + 256;
    size_t r0 = (size_t)p0 * VD + h * DVv, r1 = (size_t)p1 * VD + h * DVv;
    float a  = w0 * o_c[r0 + v0] + w1 * o_c[r1 + v0];
    float b2 = w0 * o_c[r0 + v1] + w1 * o_c[r1 + v1];
    float val = a * a + b2 * b2;
#pragma unroll
    for (int off = 1; off < 64; off <<= 1) val += __shfl_xor(val, off, 64);
    __shared__ float red[4];
    if ((threadIdx.x & 63) == 0) red[threadIdx.x >> 6] = val;
    __syncthreads();
    float total = red[0] + red[1] + red[2] + red[3];
    float rms = rsqrtf(total / 512.f + 1e-5f);
    size_t og = (size_t)t * VD + h * DVv;
    float g0 = gg[og + v0], g1 = gg[og + v1];
    ocg[og + v0] = f2bf(a  * rms * norm_w[v0] * g0 / (1.f + expf(-g0)));
    ocg[og + v1] = f2bf(b2 * rms * norm_w[v1] * g1 / (1.f + expf(-g1)));
}

// ------------------------------------------------------------------ host ----
extern "C" void kernel_launch(void* const* d_in, const int* in_sizes, int n_in,
                              void* d_out, int out_size, void* d_ws, size_t ws_size,
                              hipStream_t stream)
{
    const float* hidden   = (const float*)d_in[0];
    const float* q_w      = (const float*)d_in[1];
    const float* gate_w   = (const float*)d_in[2];
    const float* k_w      = (const float*)d_in[3];
    const float* v_w      = (const float*)d_in[4];
    const float* b_w      = (const float*)d_in[5];
    const float* a_w      = (const float*)d_in[6];
    const float* A_log    = (const float*)d_in[7];
    const float* dt_bias  = (const float*)d_in[8];
    const float* q_conv_w = (const float*)d_in[9];
    const float* k_conv_w = (const float*)d_in[10];
    const float* v_conv_w = (const float*)d_in[11];
    const float* g_w      = (const float*)d_in[12];
    const float* norm_w   = (const float*)d_in[13];
    const float* o_w      = (const float*)d_in[14];
    float* outp = (float*)d_out;

    float* f = (float*)d_ws;
    size_t off = 0;
    auto alloc = [&](size_t n) { float* p = f + off; off += (n + 3) & ~(size_t)3; return p; };
    float* qh     = alloc((size_t)1024 * 1536);
    float* kraw   = alloc((size_t)2048 * 1536);
    float* qn     = alloc((size_t)2048 * 1536);
    float* kn     = alloc((size_t)2048 * 1536);
    float* vraw   = alloc((size_t)2048 * 3072);   // reused as o_c after conv_v
    float* vconv  = alloc((size_t)2048 * 3072);
    float* gg     = alloc((size_t)1024 * 3072);
    float* beta_c = alloc(2048 * 6);
    float* g_c    = alloc(2048 * 6);
    float* qk_c   = alloc(2048 * 6);
    float* w01f   = alloc(2048);

    unsigned short* u = (unsigned short*)(f + off);
    size_t uoff = 0;
    auto ualloc = [&](size_t n) { unsigned short* p = u + uoff; uoff += (n + 7) & ~(size_t)7; return p; };
    unsigned short* hidden_bf = ualloc((size_t)1024 * 2048);
    unsigned short* xe_c      = ualloc((size_t)2048 * 2048);
    unsigned short* ocg       = ualloc((size_t)1024 * 3072);
    unsigned short* q_wT      = ualloc((size_t)2048 * 1536);
    unsigned short* k_wT      = ualloc((size_t)8 * 2048 * 1536);
    unsigned short* v_wT      = ualloc((size_t)8 * 2048 * 3072);
    unsigned short* g_wT      = ualloc((size_t)2048 * 3072);
    unsigned short* o_wT      = ualloc((size_t)3072 * 2048);

    int* ib      = (int*)(u + uoff);
    int* sel01   = ib;
    int* list_c  = ib + 2048;
    int* posg    = ib + 4096;
    int* cnt     = ib + 6144;
    int* basearr = ib + 6152;
    float* o_c = vraw;

    router_kernel<<<1024, 64, 0, stream>>>(hidden, gate_w, sel01, w01f);
    dispatch_kernel<<<1, 1024, 0, stream>>>(sel01, list_c, posg, cnt, basearr);

    cast_bf16_kernel<<<2048, 256, 0, stream>>>(hidden, hidden_bf);
    gather_cast_kernel<<<2048, 256, 0, stream>>>(hidden, list_c, xe_c);
    transpose_cast_kernel<<<dim3(64, 48, 1), 256, 0, stream>>>(q_w, q_wT, 2048, 1536);
    transpose_cast_kernel<<<dim3(64, 48, 8), 256, 0, stream>>>(k_w, k_wT, 2048, 1536);
    transpose_cast_kernel<<<dim3(64, 96, 8), 256, 0, stream>>>(v_w, v_wT, 2048, 3072);
    transpose_cast_kernel<<<dim3(64, 96, 1), 256, 0, stream>>>(g_w, g_wT, 2048, 3072);
    transpose_cast_kernel<<<dim3(96, 64, 1), 256, 0, stream>>>(o_w, o_wT, 3072, 2048);

    gemm_bf16<false><<<dim3(8, 12), 256, 0, stream>>>(hidden_bf, q_wT, qh, nullptr, nullptr, 1024, 2048, 1536);
    gemm_bf16<true ><<<dim3(8, 12, 8), 256, 0, stream>>>(xe_c, k_wT, kraw, cnt, basearr, 0, 2048, 1536);
    gemm_bf16<true ><<<dim3(8, 24, 8), 256, 0, stream>>>(xe_c, v_wT, vraw, cnt, basearr, 0, 2048, 3072);
    gemm_bf16<false><<<dim3(8, 24), 256, 0, stream>>>(hidden_bf, g_wT, gg, nullptr, nullptr, 1024, 2048, 3072);

    ba_kernel<<<dim3(1024, 8), 64, 0, stream>>>(hidden, b_w, a_w, A_log, dt_bias,
                                                list_c, cnt, basearr, beta_c, g_c);

    conv_norm_kernel<true ><<<dim3(1024, 8, 6), 256, 0, stream>>>(qh,   q_conv_w, list_c, cnt, basearr, qn, 0.0625f);
    conv_norm_kernel<false><<<dim3(1024, 8, 6), 256, 0, stream>>>(kraw, k_conv_w, list_c, cnt, basearr, kn, 1.0f);
    conv_v_kernel<<<dim3(1024, 8, 12), 256, 0, stream>>>(vraw, v_conv_w, cnt, basearr, vconv);

    qk_kernel<<<dim3(2048, 6), 64, 0, stream>>>(qn, kn, qk_c);

    recurrence_kernel<<<dim3(16, 6, 8), 256, 0, stream>>>(qn, kn, vconv, beta_c, g_c, qk_c,
                                                          cnt, basearr, o_c);

    combine_kernel<<<dim3(1024, 6), 256, 0, stream>>>(o_c, gg, norm_w, posg, w01f, ocg);
    gemm_bf16<false><<<dim3(8, 16), 256, 0, stream>>>(ocg, o_wT, outp, nullptr, nullptr, 1024, 3072, 2048);
}